// Round 1
// baseline (575.978 us; speedup 1.0000x reference)
//
#include <hip/hip_runtime.h>
#include <hip/hip_bf16.h>

// ---------------------------------------------------------------------------
// FCx2DetHead: x(8,256,25,25) --transpose--> channels-last feat(8,25,25,256)
// pool0 -> G1(relu) -> G2(relu) -> G3 -> pool1 -> G4(relu) -> G5(relu) -> G6
// GEMMs: bf16 MFMA 16x16x32, fp32 accumulate, split-K with atomicAdd into
// bias-pre-initialized C. Weights converted fp32->bf16 in-kernel (no extra
// HBM pass). All activations bf16 for MFMA A-operand, fp32 master copies.
// ---------------------------------------------------------------------------

#define NROI 256
#define CCH  256
#define HH   25
#define WW   25
#define NB   8
#define INF  12544   // 256*49
#define DFC  1024
#define FCC  512

typedef __attribute__((ext_vector_type(8))) short short8;
typedef __attribute__((ext_vector_type(4))) float floatx4;

static __device__ __forceinline__ unsigned short f2bf(float f) {
    unsigned int u = __float_as_uint(f);
    unsigned int r = (u + 0x7fffu + ((u >> 16) & 1u)) >> 16;
    return (unsigned short)r;
}

// ---------------- transpose x (B,C,H,W) -> feat (B,H,W,C) -------------------
__global__ __launch_bounds__(256) void transpose_kernel(
        const float* __restrict__ x, float* __restrict__ xT) {
    __shared__ float t[32][33];
    int b  = blockIdx.z;
    int cb = blockIdx.y * 32;     // channel tile
    int lb = blockIdx.x * 32;     // hw tile (0..624)
    int tx = threadIdx.x & 31, ty = threadIdx.x >> 5;
#pragma unroll
    for (int r = 0; r < 4; ++r) {
        int c = cb + ty + r * 8, l = lb + tx;
        if (l < 625) t[ty + r * 8][tx] = x[(size_t)(b * 256 + c) * 625 + l];
    }
    __syncthreads();
#pragma unroll
    for (int r = 0; r < 4; ++r) {
        int l = lb + ty + r * 8, c = cb + tx;
        if (l < 625) xT[((size_t)b * 625 + l) * 256 + c] = t[tx][ty + r * 8];
    }
}

// ---------------- deformable RoI pool ---------------------------------------
// One block per roi. Phase1: 784 (bin,sample) bilinear taps. Phase2: collapse
// 16 samples x 4 taps into a 4x4 pixel-weight grid per bin. Phase3: 256
// channels x 49 bins gather (coalesced 1KB loads). Output row written bf16
// coalesced via LDS. Also initializes next GEMM's C with its bias.
__global__ __launch_bounds__(256) void pool_kernel(
        const float* __restrict__ feat, const float* __restrict__ rois,
        const float* __restrict__ off, int has_off,
        unsigned short* __restrict__ P,
        float* __restrict__ initDst, const float* __restrict__ initBias, int biasN) {
    __shared__ unsigned int sPack[784];
    __shared__ float4 sW[784];
    __shared__ float sGrid[49][16];
    __shared__ int   sBase[49];
    __shared__ float sCnt[49];
    __shared__ unsigned short sOut[INF];

    const float SSC = (float)(25.0 / 255.0);
    int n = blockIdx.x, tid = threadIdx.x;
    const float* r = rois + n * 5;
    int b = (int)r[0];
    float sw = rintf(r[1]) * SSC - 0.5f;
    float sh = rintf(r[2]) * SSC - 0.5f;
    float rw = fmaxf((rintf(r[3]) + 1.0f) * SSC - 0.5f - sw, 0.1f);
    float rh = fmaxf((rintf(r[4]) + 1.0f) * SSC - 0.5f - sh, 0.1f);
    float bw = rw / 7.0f, bh = rh / 7.0f;
    float bws = bw / 4.0f, bhs = bh / 4.0f;

    for (int idx = tid; idx < 784; idx += 256) {
        int bin = idx >> 4, s = idx & 15;
        int ph = bin / 7, pw = bin - ph * 7;
        int syi = s >> 2, sxi = s & 3;
        float tx = 0.f, ty = 0.f;
        if (has_off) {
            tx = off[n * 98 + bin] * 0.1f;
            ty = off[n * 98 + 49 + bin] * 0.1f;
        }
        float fx = (pw * bw + sw + tx * rw) + sxi * bws;
        float fy = (ph * bh + sh + ty * rh) + syi * bhs;
        bool valid = (fx >= -0.5f) && (fx <= 24.5f) && (fy >= -0.5f) && (fy <= 24.5f);
        float xc = fminf(fmaxf(fx, 0.f), 24.f);
        float yc = fminf(fmaxf(fy, 0.f), 24.f);
        float x0f = floorf(xc), y0f = floorf(yc);
        float dx = xc - x0f, dy = yc - y0f;
        int x0 = (int)x0f, y0 = (int)y0f;
        int x1 = (int)ceilf(xc), y1 = (int)ceilf(yc);
        float w00 = (1.f - dx) * (1.f - dy), w01 = dx * (1.f - dy);
        float w10 = (1.f - dx) * dy,         w11 = dx * dy;
        if (!valid) { w00 = w01 = w10 = w11 = 0.f; }
        sPack[idx] = (unsigned)y0 | ((unsigned)x0 << 7) | ((unsigned)y1 << 14) |
                     ((unsigned)x1 << 21) | ((valid ? 1u : 0u) << 28);
        sW[idx] = make_float4(w00, w01, w10, w11);
    }
    __syncthreads();
    if (tid < 49) {
        unsigned p0 = sPack[tid * 16];
        int gy0 = p0 & 127, gx0 = (p0 >> 7) & 127;
#pragma unroll
        for (int i = 0; i < 16; ++i) sGrid[tid][i] = 0.f;
        int cnt = 0;
        for (int s = 0; s < 16; ++s) {
            unsigned p = sPack[tid * 16 + s];
            float4 w = sW[tid * 16 + s];
            int y0 = p & 127, x0 = (p >> 7) & 127;
            int y1 = (p >> 14) & 127, x1 = (p >> 21) & 127;
            cnt += (p >> 28) & 1;
            sGrid[tid][(y0 - gy0) * 4 + (x0 - gx0)] += w.x;
            sGrid[tid][(y0 - gy0) * 4 + (x1 - gx0)] += w.y;
            sGrid[tid][(y1 - gy0) * 4 + (x0 - gx0)] += w.z;
            sGrid[tid][(y1 - gy0) * 4 + (x1 - gx0)] += w.w;
        }
        sBase[tid] = gy0 | (gx0 << 8);
        sCnt[tid] = fmaxf((float)cnt, 1.0f);
    }
    __syncthreads();
    {
        int c = tid;
        for (int bin = 0; bin < 49; ++bin) {
            int base = sBase[bin];
            int gy0 = base & 255, gx0 = base >> 8;
            const float* fb = feat + ((size_t)((b * 25 + gy0) * 25 + gx0)) * 256 + c;
            float acc = 0.f;
#pragma unroll
            for (int cell = 0; cell < 16; ++cell) {
                float w = sGrid[bin][cell];           // LDS broadcast, wave-uniform
                if (w != 0.f)
                    acc += w * fb[((cell >> 2) * 25 + (cell & 3)) * 256];
            }
            sOut[c * 49 + bin] = f2bf(acc / sCnt[bin]);
        }
    }
    __syncthreads();
    const unsigned int* so = (const unsigned int*)sOut;
    unsigned int* dp = (unsigned int*)(P + (size_t)n * INF);
    for (int i = tid; i < INF / 2; i += 256) dp[i] = so[i];
    if (initDst)
        for (int i = tid; i < biasN; i += 256)
            initDst[(size_t)n * biasN + i] = initBias[i];
}

// ---------------- split-K MFMA GEMM: C(+)= A(bf16,MxK) * B(fp32,NxK)^T ------
template <int BM, int BN>
__global__ __launch_bounds__(256) void gemm_nt_atomic(
        const unsigned short* __restrict__ A, const float* __restrict__ Bw,
        float* __restrict__ C, int M, int N, int K, int kSteps) {
    constexpr int LDA = 40;                  // 32 + 8 pad (keeps 16B align, kills conflicts)
    __shared__ unsigned short As[BM * LDA];
    __shared__ unsigned short Bs[BN * LDA];
    const int tid = threadIdx.x;
    const int lane = tid & 63;
    const int wave = tid >> 6;
    const int wm = wave >> 1, wn = wave & 1;
    const int m0 = blockIdx.y * BM;
    const int n0 = blockIdx.x * BN;
    const int k0 = blockIdx.z * kSteps * 32;
    const int quad = lane >> 4;
    const int l16 = lane & 15;
    constexpr int FM = BM / 32, FN = BN / 32;

    floatx4 acc[FM][FN];
#pragma unroll
    for (int i = 0; i < FM; ++i)
#pragma unroll
        for (int j = 0; j < FN; ++j) acc[i][j] = (floatx4)0.f;

    for (int ks = 0; ks < kSteps; ++ks) {
        int kk = k0 + ks * 32;
        __syncthreads();
        // stage A: BM x 32 bf16 (16B quads)
#pragma unroll
        for (int i = tid; i < BM * 4; i += 256) {
            int row = i >> 2, q = i & 3;
            uint4 v = *(const uint4*)(A + (size_t)(m0 + row) * K + kk + q * 8);
            *(uint4*)(As + row * LDA + q * 8) = v;
        }
        // stage B: BN x 32 fp32 -> bf16
#pragma unroll
        for (int i = tid; i < BN * 8; i += 256) {
            int row = i >> 3, q = i & 7;
            float4 v = *(const float4*)(Bw + (size_t)(n0 + row) * K + kk + q * 4);
            ushort4 h;
            h.x = f2bf(v.x); h.y = f2bf(v.y); h.z = f2bf(v.z); h.w = f2bf(v.w);
            *(ushort4*)(Bs + row * LDA + q * 4) = h;
        }
        __syncthreads();
        short8 a[FM], bfr[FN];
#pragma unroll
        for (int i = 0; i < FM; ++i)
            a[i] = *(const short8*)(As + (wm * (BM / 2) + i * 16 + l16) * LDA + quad * 8);
#pragma unroll
        for (int j = 0; j < FN; ++j)
            bfr[j] = *(const short8*)(Bs + (wn * (BN / 2) + j * 16 + l16) * LDA + quad * 8);
#pragma unroll
        for (int i = 0; i < FM; ++i)
#pragma unroll
            for (int j = 0; j < FN; ++j)
                acc[i][j] = __builtin_amdgcn_mfma_f32_16x16x32_bf16(a[i], bfr[j], acc[i][j], 0, 0, 0);
    }
    // epilogue: C/D layout col=lane&15, row=quad*4+reg
#pragma unroll
    for (int i = 0; i < FM; ++i)
#pragma unroll
        for (int j = 0; j < FN; ++j) {
            int row0 = m0 + wm * (BM / 2) + i * 16 + quad * 4;
            int col = n0 + wn * (BN / 2) + j * 16 + l16;
#pragma unroll
            for (int rr = 0; rr < 4; ++rr)
                atomicAdd(C + (size_t)(row0 + rr) * N + col, acc[i][j][rr]);
        }
}

// ---------------- relu + bf16 cast + bias-init of next C --------------------
__global__ __launch_bounds__(256) void relu_cvt_init(
        const float* __restrict__ hin, unsigned short* __restrict__ hbf, int n1,
        float* __restrict__ dst, const float* __restrict__ bias, int biasN, int n2) {
    int idx4 = (blockIdx.x * 256 + threadIdx.x) * 4;
    if (idx4 < n1) {
        float4 v = *(const float4*)(hin + idx4);
        ushort4 h;
        h.x = f2bf(fmaxf(v.x, 0.f)); h.y = f2bf(fmaxf(v.y, 0.f));
        h.z = f2bf(fmaxf(v.z, 0.f)); h.w = f2bf(fmaxf(v.w, 0.f));
        *(ushort4*)(hbf + idx4) = h;
    }
    if (idx4 < n2) {
        int m = biasN - 1;
#pragma unroll
        for (int r = 0; r < 4; ++r) dst[idx4 + r] = bias[(idx4 + r) & m];
    }
}

// ---------------- G3: off = relu(h2) @ w3^T + b3  (256 x 98) ----------------
__global__ __launch_bounds__(128) void fc_small(
        const float* __restrict__ h2, const float* __restrict__ w3,
        const float* __restrict__ b3, float* __restrict__ out) {
    __shared__ float shl[1024];
    int n = blockIdx.x, tid = threadIdx.x;
    for (int i = tid; i < 1024; i += 128) shl[i] = fmaxf(h2[(size_t)n * 1024 + i], 0.f);
    __syncthreads();
    if (tid < 98) {
        float acc = b3[tid];
        const float* w = w3 + (size_t)tid * 1024;
        for (int k = 0; k < 1024; k += 4) {
            float4 wv = *(const float4*)(w + k);
            acc += shl[k] * wv.x + shl[k + 1] * wv.y + shl[k + 2] * wv.z + shl[k + 3] * wv.w;
        }
        out[n * 98 + tid] = acc;
    }
}

// ---------------- G6: out = relu(h4) @ box_w^T + box_b  (256 x 4) -----------
__global__ __launch_bounds__(64) void head_kernel(
        const float* __restrict__ h4, const float* __restrict__ bw,
        const float* __restrict__ bb, float* __restrict__ out) {
    int n = blockIdx.x, t = threadIdx.x;
    float a0 = 0, a1 = 0, a2 = 0, a3 = 0;
    for (int k = t; k < 512; k += 64) {
        float v = fmaxf(h4[(size_t)n * 512 + k], 0.f);
        a0 += v * bw[k]; a1 += v * bw[512 + k];
        a2 += v * bw[1024 + k]; a3 += v * bw[1536 + k];
    }
#pragma unroll
    for (int o = 32; o > 0; o >>= 1) {
        a0 += __shfl_down(a0, o); a1 += __shfl_down(a1, o);
        a2 += __shfl_down(a2, o); a3 += __shfl_down(a3, o);
    }
    if (t == 0) {
        out[n * 4 + 0] = a0 + bb[0]; out[n * 4 + 1] = a1 + bb[1];
        out[n * 4 + 2] = a2 + bb[2]; out[n * 4 + 3] = a3 + bb[3];
    }
}

// ---------------------------------------------------------------------------
extern "C" void kernel_launch(void* const* d_in, const int* in_sizes, int n_in,
                              void* d_out, int out_size, void* d_ws, size_t ws_size,
                              hipStream_t stream) {
    const float* x      = (const float*)d_in[0];
    const float* rois   = (const float*)d_in[1];
    const float* off_w1 = (const float*)d_in[2];
    const float* off_b1 = (const float*)d_in[3];
    const float* off_w2 = (const float*)d_in[4];
    const float* off_b2 = (const float*)d_in[5];
    const float* off_w3 = (const float*)d_in[6];
    const float* off_b3 = (const float*)d_in[7];
    const float* fc1_w  = (const float*)d_in[8];
    const float* fc1_b  = (const float*)d_in[9];
    const float* fc2_w  = (const float*)d_in[10];
    const float* fc2_b  = (const float*)d_in[11];
    const float* box_w  = (const float*)d_in[12];
    const float* box_b  = (const float*)d_in[13];
    float* out = (float*)d_out;

    char* ws = (char*)d_ws;
    size_t o = 0;
    auto carve = [&](size_t bytes) { char* p = ws + o; o += (bytes + 255) & ~(size_t)255; return p; };
    float*          xT   = (float*)carve((size_t)NB * 625 * 256 * 4);   // 5.12 MB
    unsigned short* p0   = (unsigned short*)carve((size_t)NROI * INF * 2);
    unsigned short* p1   = (unsigned short*)carve((size_t)NROI * INF * 2);
    float*          h1   = (float*)carve((size_t)NROI * DFC * 4);
    unsigned short* h1b  = (unsigned short*)carve((size_t)NROI * DFC * 2);
    float*          h2   = (float*)carve((size_t)NROI * DFC * 4);
    float*          offb = (float*)carve((size_t)NROI * 98 * 4);
    float*          h3   = (float*)carve((size_t)NROI * FCC * 4);
    unsigned short* h3b  = (unsigned short*)carve((size_t)NROI * FCC * 2);
    float*          h4   = (float*)carve((size_t)NROI * FCC * 4);

    // 1. channels-last transpose of x
    transpose_kernel<<<dim3(20, 8, 8), 256, 0, stream>>>(x, xT);
    // 2. pool pass 0 (zero offsets) + init h1 = b1
    pool_kernel<<<NROI, 256, 0, stream>>>(xT, rois, nullptr, 0, p0, h1, off_b1, DFC);
    // 3. G1: h1 += p0 @ off_w1^T   (256x12544x1024), KS=14 x 28 steps
    gemm_nt_atomic<128, 128><<<dim3(8, 2, 14), 256, 0, stream>>>(p0, off_w1, h1, NROI, DFC, INF, 28);
    // 4. relu(h1)->h1b ; init h2 = b2
    relu_cvt_init<<<256, 256, 0, stream>>>(h1, h1b, NROI * DFC, h2, off_b2, DFC, NROI * DFC);
    // 5. G2: h2 += h1b @ off_w2^T  (256x1024x1024), KS=8 x 4 steps
    gemm_nt_atomic<128, 128><<<dim3(8, 2, 8), 256, 0, stream>>>(h1b, off_w2, h2, NROI, DFC, DFC, 4);
    // 6. G3 (relu inline): offb = relu(h2) @ off_w3^T + b3
    fc_small<<<NROI, 128, 0, stream>>>(h2, off_w3, off_b3, offb);
    // 7. pool pass 1 (learned offsets) + init h3 = fc1_b
    pool_kernel<<<NROI, 256, 0, stream>>>(xT, rois, offb, 1, p1, h3, fc1_b, FCC);
    // 8. G4: h3 += p1 @ fc1_w^T    (256x12544x512), KS=28 x 14 steps
    gemm_nt_atomic<128, 128><<<dim3(4, 2, 28), 256, 0, stream>>>(p1, fc1_w, h3, NROI, FCC, INF, 14);
    // 9. relu(h3)->h3b ; init h4 = fc2_b
    relu_cvt_init<<<128, 256, 0, stream>>>(h3, h3b, NROI * FCC, h4, fc2_b, FCC, NROI * FCC);
    // 10. G5: h4 += h3b @ fc2_w^T  (256x512x512), KS=4 x 4 steps, 64x64 tiles
    gemm_nt_atomic<64, 64><<<dim3(8, 4, 4), 256, 0, stream>>>(h3b, fc2_w, h4, NROI, FCC, FCC, 4);
    // 11. G6: out = relu(h4) @ box_w^T + box_b
    head_kernel<<<NROI, 64, 0, stream>>>(h4, box_w, box_b, out);
}

// Round 2
// 375.884 us; speedup vs baseline: 1.5323x; 1.5323x over previous
//
#include <hip/hip_runtime.h>
#include <hip/hip_bf16.h>

// ---------------------------------------------------------------------------
// FCx2DetHead: x(8,256,25,25) --transpose--> channels-last feat(8,25,25,256)
// pool0 -> G1(relu) -> G2(relu) -> G3 -> pool1 -> G4(relu) -> G5(relu) -> G6
// GEMMs: bf16 MFMA 16x16x32, fp32 accumulate, split-K with atomicAdd into
// bias-pre-initialized C.
// Pooling split into prep (weight-grid collapse per roi,bin) + gather
// (unconditional pipelined loads, one wave per bin, float2 channels).
// ---------------------------------------------------------------------------

#define NROI 256
#define CCH  256
#define NB   8
#define INF  12544   // 256*49
#define DFC  1024
#define FCC  512

typedef __attribute__((ext_vector_type(8))) short short8;
typedef __attribute__((ext_vector_type(4))) float floatx4;

static __device__ __forceinline__ unsigned short f2bf(float f) {
    unsigned int u = __float_as_uint(f);
    unsigned int r = (u + 0x7fffu + ((u >> 16) & 1u)) >> 16;
    return (unsigned short)r;
}

// ---------------- transpose x (B,C,H,W) -> feat (B,H,W,C) -------------------
__global__ __launch_bounds__(256) void transpose_kernel(
        const float* __restrict__ x, float* __restrict__ xT) {
    __shared__ float t[32][33];
    int b  = blockIdx.z;
    int cb = blockIdx.y * 32;     // channel tile
    int lb = blockIdx.x * 32;     // hw tile (0..624)
    int tx = threadIdx.x & 31, ty = threadIdx.x >> 5;
#pragma unroll
    for (int r = 0; r < 4; ++r) {
        int c = cb + ty + r * 8, l = lb + tx;
        if (l < 625) t[ty + r * 8][tx] = x[(size_t)(b * 256 + c) * 625 + l];
    }
    __syncthreads();
#pragma unroll
    for (int r = 0; r < 4; ++r) {
        int l = lb + ty + r * 8, c = cb + tx;
        if (l < 625) xT[((size_t)b * 625 + l) * 256 + c] = t[tx][ty + r * 8];
    }
}

// ---------------- pool prep: per (roi,bin) 16-cell weight grid --------------
// 49 blocks x 256 threads; thread = one (roi,bin). Collapses 16 samples x 4
// bilinear taps into a 4x4 pixel weight grid (1/cnt folded in), writes 16
// floats + packed base (b,gy0,gx0).
__global__ __launch_bounds__(256) void pool_prep(
        const float* __restrict__ rois, const float* __restrict__ off, int has_off,
        float* __restrict__ wbuf, int* __restrict__ bbuf) {
    __shared__ float g[256][16];
    const float SSC = (float)(25.0 / 255.0);
    int tid = threadIdx.x;
    int idx = blockIdx.x * 256 + tid;          // [0, 12544)
    int n = idx / 49;
    int bin = idx - n * 49;
    const float* r = rois + n * 5;
    int b = (int)r[0];
    float sw = rintf(r[1]) * SSC - 0.5f;
    float sh = rintf(r[2]) * SSC - 0.5f;
    float rw = fmaxf((rintf(r[3]) + 1.0f) * SSC - 0.5f - sw, 0.1f);
    float rh = fmaxf((rintf(r[4]) + 1.0f) * SSC - 0.5f - sh, 0.1f);
    float bw = rw / 7.0f, bh = rh / 7.0f;
    float bws = bw * 0.25f, bhs = bh * 0.25f;
    int ph = bin / 7, pw = bin - ph * 7;
    float tx = 0.f, ty = 0.f;
    if (has_off) {
        tx = off[n * 98 + bin] * 0.1f;
        ty = off[n * 98 + 49 + bin] * 0.1f;
    }
    float wstart = pw * bw + sw + tx * rw;
    float hstart = ph * bh + sh + ty * rh;
#pragma unroll
    for (int i = 0; i < 16; ++i) g[tid][i] = 0.f;
    int gy0 = 0, gx0 = 0, cnt = 0;
#pragma unroll
    for (int s = 0; s < 16; ++s) {
        float fx = wstart + (s & 3) * bws;
        float fy = hstart + (s >> 2) * bhs;
        bool valid = (fx >= -0.5f) && (fx <= 24.5f) && (fy >= -0.5f) && (fy <= 24.5f);
        float xc = fminf(fmaxf(fx, 0.f), 24.f);
        float yc = fminf(fmaxf(fy, 0.f), 24.f);
        float x0f = floorf(xc), y0f = floorf(yc);
        float dx = xc - x0f, dy = yc - y0f;
        int x0 = (int)x0f, y0 = (int)y0f;
        int x1 = (int)ceilf(xc), y1 = (int)ceilf(yc);
        if (s == 0) { gy0 = y0; gx0 = x0; }
        float w00 = (1.f - dx) * (1.f - dy), w01 = dx * (1.f - dy);
        float w10 = (1.f - dx) * dy,         w11 = dx * dy;
        if (!valid) { w00 = w01 = w10 = w11 = 0.f; }
        cnt += valid ? 1 : 0;
        int ry0 = (y0 - gy0) * 4, ry1 = (y1 - gy0) * 4;
        g[tid][ry0 + (x0 - gx0)] += w00;
        g[tid][ry0 + (x1 - gx0)] += w01;
        g[tid][ry1 + (x0 - gx0)] += w10;
        g[tid][ry1 + (x1 - gx0)] += w11;
    }
    float inv = 1.0f / fmaxf((float)cnt, 1.0f);
    float4* wp = (float4*)(wbuf + (size_t)idx * 16);
#pragma unroll
    for (int q = 0; q < 4; ++q)
        wp[q] = make_float4(g[tid][q * 4] * inv, g[tid][q * 4 + 1] * inv,
                            g[tid][q * 4 + 2] * inv, g[tid][q * 4 + 3] * inv);
    bbuf[idx] = gy0 | (gx0 << 8) | (b << 16);
}

// ---------------- pool gather ----------------------------------------------
// grid (2 channel-halves, 256 rois) x 256 threads. Wave wv handles bins
// wv, wv+4, ... Each lane: 2 channels (float2 loads, 512B/wave/cell).
// 16 unconditional clamped loads per bin, fully unrolled. Output staged in
// LDS as bf16 (k = c*49+bin layout), one contiguous block write.
// Also initializes next GEMM's C with its bias (q==0 blocks).
__global__ __launch_bounds__(256) void pool_gather(
        const float* __restrict__ feat, const float* __restrict__ wbuf,
        const int* __restrict__ bbuf, unsigned short* __restrict__ P,
        float* __restrict__ initDst, const float* __restrict__ initBias, int biasN) {
    __shared__ unsigned short sOut[128 * 49];
    int q = blockIdx.x;            // channel half: 0 or 1
    int n = blockIdx.y;            // roi
    int tid = threadIdx.x;
    int wv = tid >> 6, lane = tid & 63;
    int cbase = q * 128 + lane * 2;

    for (int bin = wv; bin < 49; bin += 4) {
        int di = n * 49 + bin;
        int base = bbuf[di];
        int gy0 = base & 255, gx0 = (base >> 8) & 255, b = base >> 16;
        const float4* wp = (const float4*)(wbuf + (size_t)di * 16);
        float4 w0 = wp[0], w1 = wp[1], w2 = wp[2], w3 = wp[3];
        float ww[16] = { w0.x, w0.y, w0.z, w0.w, w1.x, w1.y, w1.z, w1.w,
                         w2.x, w2.y, w2.z, w2.w, w3.x, w3.y, w3.z, w3.w };
        int rowOff[4], colOff[4];
#pragma unroll
        for (int r = 0; r < 4; ++r) {
            rowOff[r] = min(gy0 + r, 24) * 25;
            colOff[r] = min(gx0 + r, 24);
        }
        int b625 = b * 625;
        float ax = 0.f, ay = 0.f;
#pragma unroll
        for (int cell = 0; cell < 16; ++cell) {
            int pix = b625 + rowOff[cell >> 2] + colOff[cell & 3];
            float2 v = *(const float2*)(feat + (size_t)pix * 256 + cbase);
            ax += ww[cell] * v.x;
            ay += ww[cell] * v.y;
        }
        sOut[(lane * 2) * 49 + bin] = f2bf(ax);
        sOut[(lane * 2 + 1) * 49 + bin] = f2bf(ay);
    }
    __syncthreads();
    const uint2* so = (const uint2*)sOut;
    uint2* dp = (uint2*)(P + (size_t)n * INF + q * 128 * 49);
    for (int i = tid; i < 128 * 49 / 4; i += 256) dp[i] = so[i];
    if (q == 0 && initDst)
        for (int i = tid; i < biasN; i += 256)
            initDst[(size_t)n * biasN + i] = initBias[i];
}

// ---------------- split-K MFMA GEMM: C(+)= A(bf16,MxK) * B(fp32,NxK)^T ------
template <int BM, int BN>
__global__ __launch_bounds__(256) void gemm_nt_atomic(
        const unsigned short* __restrict__ A, const float* __restrict__ Bw,
        float* __restrict__ C, int M, int N, int K, int kSteps) {
    constexpr int LDA = 40;                  // 32 + 8 pad
    __shared__ unsigned short As[BM * LDA];
    __shared__ unsigned short Bs[BN * LDA];
    const int tid = threadIdx.x;
    const int lane = tid & 63;
    const int wave = tid >> 6;
    const int wm = wave >> 1, wn = wave & 1;
    const int m0 = blockIdx.y * BM;
    const int n0 = blockIdx.x * BN;
    const int k0 = blockIdx.z * kSteps * 32;
    const int quad = lane >> 4;
    const int l16 = lane & 15;
    constexpr int FM = BM / 32, FN = BN / 32;

    floatx4 acc[FM][FN];
#pragma unroll
    for (int i = 0; i < FM; ++i)
#pragma unroll
        for (int j = 0; j < FN; ++j) acc[i][j] = (floatx4)0.f;

    for (int ks = 0; ks < kSteps; ++ks) {
        int kk = k0 + ks * 32;
        __syncthreads();
#pragma unroll
        for (int i = tid; i < BM * 4; i += 256) {
            int row = i >> 2, qq = i & 3;
            uint4 v = *(const uint4*)(A + (size_t)(m0 + row) * K + kk + qq * 8);
            *(uint4*)(As + row * LDA + qq * 8) = v;
        }
#pragma unroll
        for (int i = tid; i < BN * 8; i += 256) {
            int row = i >> 3, qq = i & 7;
            float4 v = *(const float4*)(Bw + (size_t)(n0 + row) * K + kk + qq * 4);
            ushort4 h;
            h.x = f2bf(v.x); h.y = f2bf(v.y); h.z = f2bf(v.z); h.w = f2bf(v.w);
            *(ushort4*)(Bs + row * LDA + qq * 4) = h;
        }
        __syncthreads();
        short8 a[FM], bfr[FN];
#pragma unroll
        for (int i = 0; i < FM; ++i)
            a[i] = *(const short8*)(As + (wm * (BM / 2) + i * 16 + l16) * LDA + quad * 8);
#pragma unroll
        for (int j = 0; j < FN; ++j)
            bfr[j] = *(const short8*)(Bs + (wn * (BN / 2) + j * 16 + l16) * LDA + quad * 8);
#pragma unroll
        for (int i = 0; i < FM; ++i)
#pragma unroll
            for (int j = 0; j < FN; ++j)
                acc[i][j] = __builtin_amdgcn_mfma_f32_16x16x32_bf16(a[i], bfr[j], acc[i][j], 0, 0, 0);
    }
#pragma unroll
    for (int i = 0; i < FM; ++i)
#pragma unroll
        for (int j = 0; j < FN; ++j) {
            int row0 = m0 + wm * (BM / 2) + i * 16 + quad * 4;
            int col = n0 + wn * (BN / 2) + j * 16 + l16;
#pragma unroll
            for (int rr = 0; rr < 4; ++rr)
                atomicAdd(C + (size_t)(row0 + rr) * N + col, acc[i][j][rr]);
        }
}

// ---------------- relu + bf16 cast + bias-init of next C --------------------
__global__ __launch_bounds__(256) void relu_cvt_init(
        const float* __restrict__ hin, unsigned short* __restrict__ hbf, int n1,
        float* __restrict__ dst, const float* __restrict__ bias, int biasN, int n2) {
    int idx4 = (blockIdx.x * 256 + threadIdx.x) * 4;
    if (idx4 < n1) {
        float4 v = *(const float4*)(hin + idx4);
        ushort4 h;
        h.x = f2bf(fmaxf(v.x, 0.f)); h.y = f2bf(fmaxf(v.y, 0.f));
        h.z = f2bf(fmaxf(v.z, 0.f)); h.w = f2bf(fmaxf(v.w, 0.f));
        *(ushort4*)(hbf + idx4) = h;
    }
    if (idx4 < n2) {
        int m = biasN - 1;
#pragma unroll
        for (int r = 0; r < 4; ++r) dst[idx4 + r] = bias[(idx4 + r) & m];
    }
}

// ---------------- G3: off = relu(h2) @ w3^T + b3  (256 x 98) ----------------
__global__ __launch_bounds__(128) void fc_small(
        const float* __restrict__ h2, const float* __restrict__ w3,
        const float* __restrict__ b3, float* __restrict__ out) {
    __shared__ float shl[1024];
    int n = blockIdx.x, tid = threadIdx.x;
    for (int i = tid; i < 1024; i += 128) shl[i] = fmaxf(h2[(size_t)n * 1024 + i], 0.f);
    __syncthreads();
    if (tid < 98) {
        float acc = b3[tid];
        const float* w = w3 + (size_t)tid * 1024;
        for (int k = 0; k < 1024; k += 4) {
            float4 wv = *(const float4*)(w + k);
            acc += shl[k] * wv.x + shl[k + 1] * wv.y + shl[k + 2] * wv.z + shl[k + 3] * wv.w;
        }
        out[n * 98 + tid] = acc;
    }
}

// ---------------- G6: out = relu(h4) @ box_w^T + box_b  (256 x 4) -----------
__global__ __launch_bounds__(64) void head_kernel(
        const float* __restrict__ h4, const float* __restrict__ bw,
        const float* __restrict__ bb, float* __restrict__ out) {
    int n = blockIdx.x, t = threadIdx.x;
    float a0 = 0, a1 = 0, a2 = 0, a3 = 0;
    for (int k = t; k < 512; k += 64) {
        float v = fmaxf(h4[(size_t)n * 512 + k], 0.f);
        a0 += v * bw[k]; a1 += v * bw[512 + k];
        a2 += v * bw[1024 + k]; a3 += v * bw[1536 + k];
    }
#pragma unroll
    for (int o = 32; o > 0; o >>= 1) {
        a0 += __shfl_down(a0, o); a1 += __shfl_down(a1, o);
        a2 += __shfl_down(a2, o); a3 += __shfl_down(a3, o);
    }
    if (t == 0) {
        out[n * 4 + 0] = a0 + bb[0]; out[n * 4 + 1] = a1 + bb[1];
        out[n * 4 + 2] = a2 + bb[2]; out[n * 4 + 3] = a3 + bb[3];
    }
}

// ---------------------------------------------------------------------------
extern "C" void kernel_launch(void* const* d_in, const int* in_sizes, int n_in,
                              void* d_out, int out_size, void* d_ws, size_t ws_size,
                              hipStream_t stream) {
    const float* x      = (const float*)d_in[0];
    const float* rois   = (const float*)d_in[1];
    const float* off_w1 = (const float*)d_in[2];
    const float* off_b1 = (const float*)d_in[3];
    const float* off_w2 = (const float*)d_in[4];
    const float* off_b2 = (const float*)d_in[5];
    const float* off_w3 = (const float*)d_in[6];
    const float* off_b3 = (const float*)d_in[7];
    const float* fc1_w  = (const float*)d_in[8];
    const float* fc1_b  = (const float*)d_in[9];
    const float* fc2_w  = (const float*)d_in[10];
    const float* fc2_b  = (const float*)d_in[11];
    const float* box_w  = (const float*)d_in[12];
    const float* box_b  = (const float*)d_in[13];
    float* out = (float*)d_out;

    char* ws = (char*)d_ws;
    size_t o = 0;
    auto carve = [&](size_t bytes) { char* p = ws + o; o += (bytes + 255) & ~(size_t)255; return p; };
    float*          xT   = (float*)carve((size_t)NB * 625 * 256 * 4);   // 5.12 MB
    unsigned short* p0   = (unsigned short*)carve((size_t)NROI * INF * 2);
    unsigned short* p1   = (unsigned short*)carve((size_t)NROI * INF * 2);
    float*          h1   = (float*)carve((size_t)NROI * DFC * 4);
    unsigned short* h1b  = (unsigned short*)carve((size_t)NROI * DFC * 2);
    float*          h2   = (float*)carve((size_t)NROI * DFC * 4);
    float*          offb = (float*)carve((size_t)NROI * 98 * 4);
    float*          h3   = (float*)carve((size_t)NROI * FCC * 4);
    unsigned short* h3b  = (unsigned short*)carve((size_t)NROI * FCC * 2);
    float*          h4   = (float*)carve((size_t)NROI * FCC * 4);
    float*          wbuf = (float*)carve((size_t)NROI * 49 * 16 * 4);   // 803 KB
    int*            bbuf = (int*)carve((size_t)NROI * 49 * 4);

    // 1. channels-last transpose of x
    transpose_kernel<<<dim3(20, 8, 8), 256, 0, stream>>>(x, xT);
    // 2. pool pass 0 (zero offsets): prep + gather (+ init h1 = b1)
    pool_prep<<<49, 256, 0, stream>>>(rois, nullptr, 0, wbuf, bbuf);
    pool_gather<<<dim3(2, NROI), 256, 0, stream>>>(xT, wbuf, bbuf, p0, h1, off_b1, DFC);
    // 3. G1: h1 += p0 @ off_w1^T   (256x12544x1024)
    gemm_nt_atomic<128, 128><<<dim3(8, 2, 14), 256, 0, stream>>>(p0, off_w1, h1, NROI, DFC, INF, 28);
    // 4. relu(h1)->h1b ; init h2 = b2
    relu_cvt_init<<<256, 256, 0, stream>>>(h1, h1b, NROI * DFC, h2, off_b2, DFC, NROI * DFC);
    // 5. G2: h2 += h1b @ off_w2^T  (256x1024x1024)
    gemm_nt_atomic<128, 128><<<dim3(8, 2, 8), 256, 0, stream>>>(h1b, off_w2, h2, NROI, DFC, DFC, 4);
    // 6. G3 (relu inline): offb = relu(h2) @ off_w3^T + b3
    fc_small<<<NROI, 128, 0, stream>>>(h2, off_w3, off_b3, offb);
    // 7. pool pass 1 (learned offsets): prep + gather (+ init h3 = fc1_b)
    pool_prep<<<49, 256, 0, stream>>>(rois, offb, 1, wbuf, bbuf);
    pool_gather<<<dim3(2, NROI), 256, 0, stream>>>(xT, wbuf, bbuf, p1, h3, fc1_b, FCC);
    // 8. G4: h3 += p1 @ fc1_w^T    (256x12544x512)
    gemm_nt_atomic<128, 128><<<dim3(4, 2, 28), 256, 0, stream>>>(p1, fc1_w, h3, NROI, FCC, INF, 14);
    // 9. relu(h3)->h3b ; init h4 = fc2_b
    relu_cvt_init<<<128, 256, 0, stream>>>(h3, h3b, NROI * FCC, h4, fc2_b, FCC, NROI * FCC);
    // 10. G5: h4 += h3b @ fc2_w^T  (256x512x512)
    gemm_nt_atomic<64, 64><<<dim3(8, 4, 4), 256, 0, stream>>>(h3b, fc2_w, h4, NROI, FCC, FCC, 4);
    // 11. G6: out = relu(h4) @ box_w^T + box_b
    head_kernel<<<NROI, 64, 0, stream>>>(h4, box_w, box_b, out);
}

// Round 3
// 351.860 us; speedup vs baseline: 1.6370x; 1.0683x over previous
//
#include <hip/hip_runtime.h>
#include <hip/hip_bf16.h>

// ---------------------------------------------------------------------------
// FCx2DetHead: x(8,256,25,25) --transpose--> channels-last feat(8,25,25,256)
// pool0 -> G1(relu) -> G2(relu) -> G3 -> pool1 -> G4(relu) -> G5(relu) -> G6
// GEMMs: bf16 MFMA 16x16x32, fp32 accumulate, split-K with atomicAdd into
// bias-pre-initialized C. Register-prefetch pipeline: tile k+1 global->VGPR
// issued during tile k's MFMA phase (latency was the R2 bottleneck: 9%
// occupancy, 2.5% MfmaUtil, serialized k-steps).
// ---------------------------------------------------------------------------

#define NROI 256
#define CCH  256
#define NB   8
#define INF  12544   // 256*49
#define DFC  1024
#define FCC  512

typedef __attribute__((ext_vector_type(8))) short short8;
typedef __attribute__((ext_vector_type(4))) float floatx4;

static __device__ __forceinline__ unsigned short f2bf(float f) {
    unsigned int u = __float_as_uint(f);
    unsigned int r = (u + 0x7fffu + ((u >> 16) & 1u)) >> 16;
    return (unsigned short)r;
}

// ---------------- transpose x (B,C,H,W) -> feat (B,H,W,C) -------------------
__global__ __launch_bounds__(256) void transpose_kernel(
        const float* __restrict__ x, float* __restrict__ xT) {
    __shared__ float t[32][33];
    int b  = blockIdx.z;
    int cb = blockIdx.y * 32;     // channel tile
    int lb = blockIdx.x * 32;     // hw tile (0..624)
    int tx = threadIdx.x & 31, ty = threadIdx.x >> 5;
#pragma unroll
    for (int r = 0; r < 4; ++r) {
        int c = cb + ty + r * 8, l = lb + tx;
        if (l < 625) t[ty + r * 8][tx] = x[(size_t)(b * 256 + c) * 625 + l];
    }
    __syncthreads();
#pragma unroll
    for (int r = 0; r < 4; ++r) {
        int l = lb + ty + r * 8, c = cb + tx;
        if (l < 625) xT[((size_t)b * 625 + l) * 256 + c] = t[tx][ty + r * 8];
    }
}

// ---------------- pool prep: per (roi,bin) 16-cell weight grid --------------
__global__ __launch_bounds__(256) void pool_prep(
        const float* __restrict__ rois, const float* __restrict__ off, int has_off,
        float* __restrict__ wbuf, int* __restrict__ bbuf) {
    __shared__ float g[256][16];
    const float SSC = (float)(25.0 / 255.0);
    int tid = threadIdx.x;
    int idx = blockIdx.x * 256 + tid;          // [0, 12544)
    int n = idx / 49;
    int bin = idx - n * 49;
    const float* r = rois + n * 5;
    int b = (int)r[0];
    float sw = rintf(r[1]) * SSC - 0.5f;
    float sh = rintf(r[2]) * SSC - 0.5f;
    float rw = fmaxf((rintf(r[3]) + 1.0f) * SSC - 0.5f - sw, 0.1f);
    float rh = fmaxf((rintf(r[4]) + 1.0f) * SSC - 0.5f - sh, 0.1f);
    float bw = rw / 7.0f, bh = rh / 7.0f;
    float bws = bw * 0.25f, bhs = bh * 0.25f;
    int ph = bin / 7, pw = bin - ph * 7;
    float tx = 0.f, ty = 0.f;
    if (has_off) {
        tx = off[n * 98 + bin] * 0.1f;
        ty = off[n * 98 + 49 + bin] * 0.1f;
    }
    float wstart = pw * bw + sw + tx * rw;
    float hstart = ph * bh + sh + ty * rh;
#pragma unroll
    for (int i = 0; i < 16; ++i) g[tid][i] = 0.f;
    int gy0 = 0, gx0 = 0, cnt = 0;
#pragma unroll
    for (int s = 0; s < 16; ++s) {
        float fx = wstart + (s & 3) * bws;
        float fy = hstart + (s >> 2) * bhs;
        bool valid = (fx >= -0.5f) && (fx <= 24.5f) && (fy >= -0.5f) && (fy <= 24.5f);
        float xc = fminf(fmaxf(fx, 0.f), 24.f);
        float yc = fminf(fmaxf(fy, 0.f), 24.f);
        float x0f = floorf(xc), y0f = floorf(yc);
        float dx = xc - x0f, dy = yc - y0f;
        int x0 = (int)x0f, y0 = (int)y0f;
        int x1 = (int)ceilf(xc), y1 = (int)ceilf(yc);
        if (s == 0) { gy0 = y0; gx0 = x0; }
        float w00 = (1.f - dx) * (1.f - dy), w01 = dx * (1.f - dy);
        float w10 = (1.f - dx) * dy,         w11 = dx * dy;
        if (!valid) { w00 = w01 = w10 = w11 = 0.f; }
        cnt += valid ? 1 : 0;
        int ry0 = (y0 - gy0) * 4, ry1 = (y1 - gy0) * 4;
        g[tid][ry0 + (x0 - gx0)] += w00;
        g[tid][ry0 + (x1 - gx0)] += w01;
        g[tid][ry1 + (x0 - gx0)] += w10;
        g[tid][ry1 + (x1 - gx0)] += w11;
    }
    float inv = 1.0f / fmaxf((float)cnt, 1.0f);
    float4* wp = (float4*)(wbuf + (size_t)idx * 16);
#pragma unroll
    for (int q = 0; q < 4; ++q)
        wp[q] = make_float4(g[tid][q * 4] * inv, g[tid][q * 4 + 1] * inv,
                            g[tid][q * 4 + 2] * inv, g[tid][q * 4 + 3] * inv);
    bbuf[idx] = gy0 | (gx0 << 8) | (b << 16);
}

// ---------------- pool gather ----------------------------------------------
__global__ __launch_bounds__(256) void pool_gather(
        const float* __restrict__ feat, const float* __restrict__ wbuf,
        const int* __restrict__ bbuf, unsigned short* __restrict__ P,
        float* __restrict__ initDst, const float* __restrict__ initBias, int biasN) {
    __shared__ unsigned short sOut[128 * 49];
    int q = blockIdx.x;            // channel half: 0 or 1
    int n = blockIdx.y;            // roi
    int tid = threadIdx.x;
    int wv = tid >> 6, lane = tid & 63;
    int cbase = q * 128 + lane * 2;

    for (int bin = wv; bin < 49; bin += 4) {
        int di = n * 49 + bin;
        int base = bbuf[di];
        int gy0 = base & 255, gx0 = (base >> 8) & 255, b = base >> 16;
        const float4* wp = (const float4*)(wbuf + (size_t)di * 16);
        float4 w0 = wp[0], w1 = wp[1], w2 = wp[2], w3 = wp[3];
        float ww[16] = { w0.x, w0.y, w0.z, w0.w, w1.x, w1.y, w1.z, w1.w,
                         w2.x, w2.y, w2.z, w2.w, w3.x, w3.y, w3.z, w3.w };
        int rowOff[4], colOff[4];
#pragma unroll
        for (int r = 0; r < 4; ++r) {
            rowOff[r] = min(gy0 + r, 24) * 25;
            colOff[r] = min(gx0 + r, 24);
        }
        int b625 = b * 625;
        float ax = 0.f, ay = 0.f;
#pragma unroll
        for (int cell = 0; cell < 16; ++cell) {
            int pix = b625 + rowOff[cell >> 2] + colOff[cell & 3];
            float2 v = *(const float2*)(feat + (size_t)pix * 256 + cbase);
            ax += ww[cell] * v.x;
            ay += ww[cell] * v.y;
        }
        sOut[(lane * 2) * 49 + bin] = f2bf(ax);
        sOut[(lane * 2 + 1) * 49 + bin] = f2bf(ay);
    }
    __syncthreads();
    const uint2* so = (const uint2*)sOut;
    uint2* dp = (uint2*)(P + (size_t)n * INF + q * 128 * 49);
    for (int i = tid; i < 128 * 49 / 4; i += 256) dp[i] = so[i];
    if (q == 0 && initDst)
        for (int i = tid; i < biasN; i += 256)
            initDst[(size_t)n * biasN + i] = initBias[i];
}

// ---------------- split-K MFMA GEMM: C(+)= A(bf16,MxK) * B(fp32,NxK)^T ------
// Register-prefetch pipeline: tile ks+1's global loads are issued right after
// barrier1 and retire during tile ks's MFMA phase (WAR on ra/rb keeps order).
template <int BM, int BN>
__global__ __launch_bounds__(256) void gemm_nt_atomic(
        const unsigned short* __restrict__ A, const float* __restrict__ Bw,
        float* __restrict__ C, int M, int N, int K, int kSteps) {
    constexpr int LDA = 40;                  // 32 + 8 pad
    __shared__ unsigned short As[BM * LDA];
    __shared__ unsigned short Bs[BN * LDA];
    const int tid = threadIdx.x;
    const int lane = tid & 63;
    const int wave = tid >> 6;
    const int wm = wave >> 1, wn = wave & 1;
    const int m0 = blockIdx.y * BM;
    const int n0 = blockIdx.x * BN;
    const int k0 = blockIdx.z * kSteps * 32;
    const int quad = lane >> 4;
    const int l16 = lane & 15;
    constexpr int FM = BM / 32, FN = BN / 32;
    constexpr int NA = BM * 4 / 256;   // uint4 A-loads per thread
    constexpr int NBq = BN * 8 / 256;  // float4 B-loads per thread

    floatx4 acc[FM][FN];
#pragma unroll
    for (int i = 0; i < FM; ++i)
#pragma unroll
        for (int j = 0; j < FN; ++j) acc[i][j] = (floatx4)0.f;

    uint4  ra[NA];
    float4 rb[NBq];
    auto loadTile = [&](int kk) {
#pragma unroll
        for (int i = 0; i < NA; ++i) {
            int idx = tid + i * 256, row = idx >> 2, qq = idx & 3;
            ra[i] = *(const uint4*)(A + (size_t)(m0 + row) * K + kk + qq * 8);
        }
#pragma unroll
        for (int i = 0; i < NBq; ++i) {
            int idx = tid + i * 256, row = idx >> 3, qq = idx & 7;
            rb[i] = *(const float4*)(Bw + (size_t)(n0 + row) * K + kk + qq * 4);
        }
    };

    loadTile(k0);
    for (int ks = 0; ks < kSteps; ++ks) {
        // stage prefetched tile into LDS (f2bf for B here, overlapping loads)
#pragma unroll
        for (int i = 0; i < NA; ++i) {
            int idx = tid + i * 256, row = idx >> 2, qq = idx & 3;
            *(uint4*)(As + row * LDA + qq * 8) = ra[i];
        }
#pragma unroll
        for (int i = 0; i < NBq; ++i) {
            int idx = tid + i * 256, row = idx >> 3, qq = idx & 7;
            ushort4 h;
            h.x = f2bf(rb[i].x); h.y = f2bf(rb[i].y);
            h.z = f2bf(rb[i].z); h.w = f2bf(rb[i].w);
            *(ushort4*)(Bs + row * LDA + qq * 4) = h;
        }
        __syncthreads();
        if (ks + 1 < kSteps) loadTile(k0 + (ks + 1) * 32);   // overlap w/ MFMA
        short8 a[FM], bfr[FN];
#pragma unroll
        for (int i = 0; i < FM; ++i)
            a[i] = *(const short8*)(As + (wm * (BM / 2) + i * 16 + l16) * LDA + quad * 8);
#pragma unroll
        for (int j = 0; j < FN; ++j)
            bfr[j] = *(const short8*)(Bs + (wn * (BN / 2) + j * 16 + l16) * LDA + quad * 8);
#pragma unroll
        for (int i = 0; i < FM; ++i)
#pragma unroll
            for (int j = 0; j < FN; ++j)
                acc[i][j] = __builtin_amdgcn_mfma_f32_16x16x32_bf16(a[i], bfr[j], acc[i][j], 0, 0, 0);
        __syncthreads();
    }
#pragma unroll
    for (int i = 0; i < FM; ++i)
#pragma unroll
        for (int j = 0; j < FN; ++j) {
            int row0 = m0 + wm * (BM / 2) + i * 16 + quad * 4;
            int col = n0 + wn * (BN / 2) + j * 16 + l16;
#pragma unroll
            for (int rr = 0; rr < 4; ++rr)
                atomicAdd(C + (size_t)(row0 + rr) * N + col, acc[i][j][rr]);
        }
}

// ---------------- relu + bf16 cast + bias-init of next C --------------------
__global__ __launch_bounds__(256) void relu_cvt_init(
        const float* __restrict__ hin, unsigned short* __restrict__ hbf, int n1,
        float* __restrict__ dst, const float* __restrict__ bias, int biasN, int n2) {
    int idx4 = (blockIdx.x * 256 + threadIdx.x) * 4;
    if (idx4 < n1) {
        float4 v = *(const float4*)(hin + idx4);
        ushort4 h;
        h.x = f2bf(fmaxf(v.x, 0.f)); h.y = f2bf(fmaxf(v.y, 0.f));
        h.z = f2bf(fmaxf(v.z, 0.f)); h.w = f2bf(fmaxf(v.w, 0.f));
        *(ushort4*)(hbf + idx4) = h;
    }
    if (idx4 < n2) {
        int m = biasN - 1;
#pragma unroll
        for (int r = 0; r < 4; ++r) dst[idx4 + r] = bias[(idx4 + r) & m];
    }
}

// ---------------- G3: off = relu(h2) @ w3^T + b3  (256 x 98) ----------------
__global__ __launch_bounds__(128) void fc_small(
        const float* __restrict__ h2, const float* __restrict__ w3,
        const float* __restrict__ b3, float* __restrict__ out) {
    __shared__ float shl[1024];
    int n = blockIdx.x, tid = threadIdx.x;
    for (int i = tid; i < 1024; i += 128) shl[i] = fmaxf(h2[(size_t)n * 1024 + i], 0.f);
    __syncthreads();
    if (tid < 98) {
        float acc = b3[tid];
        const float* w = w3 + (size_t)tid * 1024;
        for (int k = 0; k < 1024; k += 4) {
            float4 wv = *(const float4*)(w + k);
            acc += shl[k] * wv.x + shl[k + 1] * wv.y + shl[k + 2] * wv.z + shl[k + 3] * wv.w;
        }
        out[n * 98 + tid] = acc;
    }
}

// ---------------- G6: out = relu(h4) @ box_w^T + box_b  (256 x 4) -----------
__global__ __launch_bounds__(64) void head_kernel(
        const float* __restrict__ h4, const float* __restrict__ bw,
        const float* __restrict__ bb, float* __restrict__ out) {
    int n = blockIdx.x, t = threadIdx.x;
    float a0 = 0, a1 = 0, a2 = 0, a3 = 0;
    for (int k = t; k < 512; k += 64) {
        float v = fmaxf(h4[(size_t)n * 512 + k], 0.f);
        a0 += v * bw[k]; a1 += v * bw[512 + k];
        a2 += v * bw[1024 + k]; a3 += v * bw[1536 + k];
    }
#pragma unroll
    for (int o = 32; o > 0; o >>= 1) {
        a0 += __shfl_down(a0, o); a1 += __shfl_down(a1, o);
        a2 += __shfl_down(a2, o); a3 += __shfl_down(a3, o);
    }
    if (t == 0) {
        out[n * 4 + 0] = a0 + bb[0]; out[n * 4 + 1] = a1 + bb[1];
        out[n * 4 + 2] = a2 + bb[2]; out[n * 4 + 3] = a3 + bb[3];
    }
}

// ---------------------------------------------------------------------------
extern "C" void kernel_launch(void* const* d_in, const int* in_sizes, int n_in,
                              void* d_out, int out_size, void* d_ws, size_t ws_size,
                              hipStream_t stream) {
    const float* x      = (const float*)d_in[0];
    const float* rois   = (const float*)d_in[1];
    const float* off_w1 = (const float*)d_in[2];
    const float* off_b1 = (const float*)d_in[3];
    const float* off_w2 = (const float*)d_in[4];
    const float* off_b2 = (const float*)d_in[5];
    const float* off_w3 = (const float*)d_in[6];
    const float* off_b3 = (const float*)d_in[7];
    const float* fc1_w  = (const float*)d_in[8];
    const float* fc1_b  = (const float*)d_in[9];
    const float* fc2_w  = (const float*)d_in[10];
    const float* fc2_b  = (const float*)d_in[11];
    const float* box_w  = (const float*)d_in[12];
    const float* box_b  = (const float*)d_in[13];
    float* out = (float*)d_out;

    char* ws = (char*)d_ws;
    size_t o = 0;
    auto carve = [&](size_t bytes) { char* p = ws + o; o += (bytes + 255) & ~(size_t)255; return p; };
    float*          xT   = (float*)carve((size_t)NB * 625 * 256 * 4);   // 5.12 MB
    unsigned short* p0   = (unsigned short*)carve((size_t)NROI * INF * 2);
    unsigned short* p1   = (unsigned short*)carve((size_t)NROI * INF * 2);
    float*          h1   = (float*)carve((size_t)NROI * DFC * 4);
    unsigned short* h1b  = (unsigned short*)carve((size_t)NROI * DFC * 2);
    float*          h2   = (float*)carve((size_t)NROI * DFC * 4);
    float*          offb = (float*)carve((size_t)NROI * 98 * 4);
    float*          h3   = (float*)carve((size_t)NROI * FCC * 4);
    unsigned short* h3b  = (unsigned short*)carve((size_t)NROI * FCC * 2);
    float*          h4   = (float*)carve((size_t)NROI * FCC * 4);
    float*          wbuf = (float*)carve((size_t)NROI * 49 * 16 * 4);   // 803 KB
    int*            bbuf = (int*)carve((size_t)NROI * 49 * 4);

    // 1. channels-last transpose of x
    transpose_kernel<<<dim3(20, 8, 8), 256, 0, stream>>>(x, xT);
    // 2. pool pass 0 (zero offsets): prep + gather (+ init h1 = b1)
    pool_prep<<<49, 256, 0, stream>>>(rois, nullptr, 0, wbuf, bbuf);
    pool_gather<<<dim3(2, NROI), 256, 0, stream>>>(xT, wbuf, bbuf, p0, h1, off_b1, DFC);
    // 3. G1: h1 += p0 @ off_w1^T   (256x12544x1024)  896 blocks, 3.5/CU
    gemm_nt_atomic<128, 64><<<dim3(16, 2, 28), 256, 0, stream>>>(p0, off_w1, h1, NROI, DFC, INF, 14);
    // 4. relu(h1)->h1b ; init h2 = b2
    relu_cvt_init<<<256, 256, 0, stream>>>(h1, h1b, NROI * DFC, h2, off_b2, DFC, NROI * DFC);
    // 5. G2: h2 += h1b @ off_w2^T  (256x1024x1024)  512 blocks
    gemm_nt_atomic<128, 64><<<dim3(16, 2, 16), 256, 0, stream>>>(h1b, off_w2, h2, NROI, DFC, DFC, 2);
    // 6. G3 (relu inline): offb = relu(h2) @ off_w3^T + b3
    fc_small<<<NROI, 128, 0, stream>>>(h2, off_w3, off_b3, offb);
    // 7. pool pass 1 (learned offsets): prep + gather (+ init h3 = fc1_b)
    pool_prep<<<49, 256, 0, stream>>>(rois, offb, 1, wbuf, bbuf);
    pool_gather<<<dim3(2, NROI), 256, 0, stream>>>(xT, wbuf, bbuf, p1, h3, fc1_b, FCC);
    // 8. G4: h3 += p1 @ fc1_w^T    (256x12544x512)  784 blocks, 3.06/CU
    gemm_nt_atomic<128, 64><<<dim3(8, 2, 49), 256, 0, stream>>>(p1, fc1_w, h3, NROI, FCC, INF, 8);
    // 9. relu(h3)->h3b ; init h4 = fc2_b
    relu_cvt_init<<<128, 256, 0, stream>>>(h3, h3b, NROI * FCC, h4, fc2_b, FCC, NROI * FCC);
    // 10. G5: h4 += h3b @ fc2_w^T  (256x512x512)  256 blocks
    gemm_nt_atomic<64, 64><<<dim3(8, 4, 8), 256, 0, stream>>>(h3b, fc2_w, h4, NROI, FCC, FCC, 2);
    // 11. G6: out = relu(h4) @ box_w^T + box_b
    head_kernel<<<NROI, 64, 0, stream>>>(h4, box_w, box_b, out);
}